// Round 18
// baseline (236.141 us; speedup 1.0000x reference)
//
#include <hip/hip_runtime.h>

typedef unsigned short u16;
typedef __attribute__((ext_vector_type(8))) short short8x;
typedef __attribute__((ext_vector_type(4))) float f32x4;

#define B_ 2
#define L_ 2048
#define HID_ 2048
#define H_ 8
#define HD_ 256

__device__ __forceinline__ u16 f2bf(float f) {
  union { float f; unsigned u; } v; v.f = f;
  unsigned r = v.u + 0x7FFFu + ((v.u >> 16) & 1u);
  return (u16)(r >> 16);
}
__device__ __forceinline__ float bf2f(u16 u) {
  union { unsigned u; float f; } v; v.u = ((unsigned)u) << 16;
  return v.f;
}

// async global->LDS, 16B per lane. lds ptr must be the wave-uniform base;
// HW adds lane*16.
__device__ __forceinline__ void gload_lds16(const void* g, void* l) {
  __builtin_amdgcn_global_load_lds((const __attribute__((address_space(1))) unsigned*)g,
                                   (__attribute__((address_space(3))) unsigned*)l, 16, 0, 0);
}

// x fp32 -> bf16, same layout. grid = nelem/4/256
__global__ __launch_bounds__(256) void cvt_x_kernel(const float4* __restrict__ in,
                                                    u16* __restrict__ out) {
  int idx = blockIdx.x * 256 + threadIdx.x;
  float4 v = in[idx];
  u16* o = out + (size_t)idx * 4;
  o[0] = f2bf(v.x); o[1] = f2bf(v.y); o[2] = f2bf(v.z); o[3] = f2bf(v.w);
}

// rope cos/sin table: tab[l*128+d] = {cos(l*f_d), sin(l*f_d)}. grid 1024x256.
__global__ __launch_bounds__(256) void rope_tab_kernel(float2* __restrict__ tab) {
  int idx = blockIdx.x * 256 + threadIdx.x;  // l*128 + d
  int d = idx & 127;
  int l = idx >> 7;
  float f = exp2f(-(float)d * (13.287712379549449f / 128.0f));
  float s, c;
  sincosf((float)l * f, &s, &c);
  tab[idx] = make_float2(c, s);
}

// W fp32 [K][N] -> Wt bf16 [N][K] (row stride K). grid (N/32, K/32), block (32,8)
__global__ __launch_bounds__(256) void cvt_wt_kernel(const float* __restrict__ W,
                                                     u16* __restrict__ Wt, int K, int N) {
  __shared__ float tile[32][33];
  int n0 = blockIdx.x * 32, k0 = blockIdx.y * 32;
  int tx = threadIdx.x, ty = threadIdx.y;
#pragma unroll
  for (int i = 0; i < 32; i += 8)
    tile[ty + i][tx] = W[(size_t)(k0 + ty + i) * N + n0 + tx];
  __syncthreads();
#pragma unroll
  for (int i = 0; i < 32; i += 8)
    Wt[(size_t)(n0 + ty + i) * K + k0 + tx] = f2bf(tile[tx][ty + i]);
}

// Merged K-rope + V-transpose prep (one launch instead of two).
// blockIdx.z == 0..1: V-transpose (32x32 LDS tile; z = batch).
// blockIdx.z == 2..3: K rope (table-based; z-2 selects half of rows).
__global__ __launch_bounds__(256) void prep_kv_kernel(const u16* __restrict__ qkvproj,
                                                      u16* __restrict__ kb,
                                                      u16* __restrict__ vt,
                                                      const float2* __restrict__ tab) {
  if (blockIdx.z >= 2) {
    // K rope: 2 z-slices x 1024 x-blocks x 256 thr = 2048*256 elems (d<128 half)
    int idx = ((blockIdx.z - 2) * 1024 + blockIdx.x) * 256 + threadIdx.x;
    int d = idx & 127;
    int row = idx >> 7;  // b*L + l
    int l = row & (L_ - 1);
    int b = row >> 11;
    size_t ibase = (size_t)row * 2560 + 2048 + d;
    float x1 = bf2f(qkvproj[ibase]);
    float x2 = bf2f(qkvproj[ibase + 128]);
    float2 cs = tab[l * 128 + d];
    size_t obase = ((size_t)b * L_ + l) * 256 + d;
    kb[obase] = f2bf(x1 * cs.x - x2 * cs.y);
    kb[obase + 128] = f2bf(x2 * cs.x + x1 * cs.y);
    return;
  }
  // V transpose: grid.x = 64 (l-tiles), grid.y = 8 (d-tiles), z = batch
  __shared__ u16 tile[32][33];
  int l0 = (blockIdx.x & 63) * 32, d0 = blockIdx.y * 32, b = blockIdx.z;
  int tx = threadIdx.x & 31, ty = threadIdx.x >> 5;
#pragma unroll
  for (int i = 0; i < 32; i += 8)
    tile[ty + i][tx] = qkvproj[((size_t)b * 2048 + l0 + ty + i) * 2560 + 2304 + d0 + tx];
  __syncthreads();
#pragma unroll
  for (int i = 0; i < 32; i += 8)
    vt[((size_t)b * 256 + d0 + ty + i) * 2048 + l0 + tx] = tile[tx][ty + i];
}

// C[M][N] = A[M][K] @ Bt[N][K]^T — 256x128 tile, BK=64, 8 waves (4M x 2N,
// wave = 64x64, acc[4][4]), TRIPLE-buffered staging with counted vmcnt (T4).
// (R13 config — best measured on these shapes.)
template <int F32OUT>
__global__ __launch_bounds__(512) void gemmtb_kernel(const u16* __restrict__ A,
                                                     const u16* __restrict__ Bt,
                                                     void* __restrict__ Cv,
                                                     int M, int N, int K) {
  __shared__ __attribute__((aligned(16))) u16 As[3][256 * 64];
  __shared__ __attribute__((aligned(16))) u16 Bs[3][128 * 64];
  const int tid = threadIdx.x, lane = tid & 63, w = tid >> 6;
  const int wr = w >> 1, wc = w & 1;
  const int l15 = lane & 15, l4 = lane >> 4;
  // XCD-aware swizzle (bijective; nwg%8==0 in all our launches)
  const int nbx = gridDim.x;
  int flat = blockIdx.y * nbx + blockIdx.x;
  int nwg = nbx * gridDim.y;
  int q8 = nwg >> 3, r8 = nwg & 7;
  int xcd = flat & 7, idx8 = flat >> 3;
  int neu = (xcd < r8 ? xcd * (q8 + 1) : r8 * (q8 + 1) + (xcd - r8) * q8) + idx8;
  const int m0 = (neu / nbx) * 256, n0 = (neu % nbx) * 128;
  const int NT = K >> 6;

  f32x4 acc[4][4] = {};
  short8x a[4][2], b[4][2];

#define STAGE_A(t, s)                                                           \
  {                                                                             \
    _Pragma("unroll") for (int i = 0; i < 4; ++i) {                             \
      int c = i * 512 + tid;                                                    \
      int row = c >> 3, j = (c & 7) ^ (row & 7);                                \
      gload_lds16(A + (size_t)(m0 + row) * K + (t) * 64 + j * 8,                \
                  (char*)&As[s][0] + (i * 512 + w * 64) * 16);                  \
    }                                                                           \
  }
#define STAGE_B(t, s)                                                           \
  {                                                                             \
    _Pragma("unroll") for (int i = 0; i < 2; ++i) {                             \
      int c = i * 512 + tid;                                                    \
      int row = c >> 3, j = (c & 7) ^ (row & 7);                                \
      gload_lds16(Bt + (size_t)(n0 + row) * K + (t) * 64 + j * 8,               \
                  (char*)&Bs[s][0] + (i * 512 + w * 64) * 16);                  \
    }                                                                           \
  }
#define RD_A(s, mi, ks)                                                         \
  (*(const short8x*)((const char*)&As[s][0] +                                   \
      ((((wr * 64 + (mi) * 16 + l15) * 128 + ((ks) * 4 + l4) * 16)) ^           \
       ((l15 & 7) << 4))))
#define RD_B(s, ni, ks)                                                         \
  (*(const short8x*)((const char*)&Bs[s][0] +                                   \
      ((((wc * 64 + (ni) * 16 + l15) * 128 + ((ks) * 4 + l4) * 16)) ^           \
       ((l15 & 7) << 4))))

  STAGE_A(0, 0);
  STAGE_B(0, 0);
  STAGE_A(1, 1);
  STAGE_B(1, 1);
  asm volatile("s_waitcnt vmcnt(6)" ::: "memory");
  __builtin_amdgcn_s_barrier();

  for (int t = 0; t < NT; ++t) {
    const int cur = t % 3, nxt = (t + 2) % 3;
    const bool ns = (t + 2 < NT);
#pragma unroll
    for (int mi = 0; mi < 4; ++mi) { a[mi][0] = RD_A(cur, mi, 0); a[mi][1] = RD_A(cur, mi, 1); }
#pragma unroll
    for (int ni = 0; ni < 2; ++ni) { b[ni][0] = RD_B(cur, ni, 0); b[ni][1] = RD_B(cur, ni, 1); }
    if (ns) STAGE_A(t + 2, nxt);
    __builtin_amdgcn_s_barrier();
    __builtin_amdgcn_s_setprio(1);
#pragma unroll
    for (int mi = 0; mi < 4; ++mi)
#pragma unroll
      for (int ni = 0; ni < 2; ++ni) {
        acc[mi][ni] = __builtin_amdgcn_mfma_f32_16x16x32_bf16(a[mi][0], b[ni][0], acc[mi][ni], 0, 0, 0);
        acc[mi][ni] = __builtin_amdgcn_mfma_f32_16x16x32_bf16(a[mi][1], b[ni][1], acc[mi][ni], 0, 0, 0);
      }
    __builtin_amdgcn_s_setprio(0);
    __builtin_amdgcn_s_barrier();
#pragma unroll
    for (int ni = 2; ni < 4; ++ni) { b[ni][0] = RD_B(cur, ni, 0); b[ni][1] = RD_B(cur, ni, 1); }
    if (ns) STAGE_B(t + 2, nxt);
    __builtin_amdgcn_s_barrier();
    __builtin_amdgcn_s_setprio(1);
#pragma unroll
    for (int mi = 0; mi < 4; ++mi)
#pragma unroll
      for (int ni = 2; ni < 4; ++ni) {
        acc[mi][ni] = __builtin_amdgcn_mfma_f32_16x16x32_bf16(a[mi][0], b[ni][0], acc[mi][ni], 0, 0, 0);
        acc[mi][ni] = __builtin_amdgcn_mfma_f32_16x16x32_bf16(a[mi][1], b[ni][1], acc[mi][ni], 0, 0, 0);
      }
    __builtin_amdgcn_s_setprio(0);
    if (ns) asm volatile("s_waitcnt vmcnt(6)" ::: "memory");
    else    asm volatile("s_waitcnt vmcnt(0)" ::: "memory");
    __builtin_amdgcn_s_barrier();
  }
#pragma unroll
  for (int mi = 0; mi < 4; ++mi) {
#pragma unroll
    for (int ni = 0; ni < 4; ++ni) {
      int gcol = n0 + wc * 64 + ni * 16 + l15;
#pragma unroll
      for (int r = 0; r < 4; ++r) {
        int grow = m0 + wr * 64 + mi * 16 + l4 * 4 + r;
        if (F32OUT)
          ((float*)Cv)[(size_t)grow * N + gcol] = acc[mi][ni][r];
        else
          ((u16*)Cv)[(size_t)grow * N + gcol] = f2bf(acc[mi][ni][r]);
      }
    }
  }
#undef STAGE_A
#undef STAGE_B
#undef RD_A
#undef RD_B
}

// Flash attention v17 — v16 with STAGE(0) hoisted ABOVE the Q-load/rope chain:
// tile-0 K/V DMA flies while the per-wave rope computation runs in registers.
// The vmcnt(0)+syncthreads before the loop drains everything as before.
__global__ __launch_bounds__(512) void flash_kernel(const u16* __restrict__ qkv,
                                                    const u16* __restrict__ kb,
                                                    const u16* __restrict__ vt,
                                                    const float2* __restrict__ tab,
                                                    u16* __restrict__ attn_o) {
  __shared__ __attribute__((aligned(16))) u16 Kbuf[2][64 * 256];  // [k][d], read ^(k&7)<<4
  __shared__ __attribute__((aligned(16))) u16 Vbuf[2][256 * 64];  // [d][k], read ^(d&7)<<4
  __shared__ __attribute__((aligned(16))) u16 Ps[8 * 16 * 64];    // per-wave [q16][kv64], ^(q&7)<<4
  const int x = blockIdx.x;
  const int p = x >> 4;               // pair index 0..15
  const int bh = x & 15;
  const int b = bh >> 3;
  const int h = bh & 7;
  const int tid = threadIdx.x, lane = tid & 63, w = tid >> 6;
  const int l15 = lane & 15, l4 = lane >> 4;
  const int j = (w < 4) ? (31 - p) : p;   // this wave's 64-row q-block
  const int q0 = j * 64 + (w & 3) * 16;
  const int nt = (31 - p) + 1;            // shared k-step count (heavy bound)

  const u16* kbase = kb + (size_t)b * (L_ * 256);
  const u16* vbase = vt + (size_t)b * (256 * L_);

#define STAGE(t, s)                                                            \
  {                                                                            \
    _Pragma("unroll") for (int i2 = 0; i2 < 4; ++i2) {                         \
      int c = i2 * 512 + tid;                                                  \
      int rk = c >> 5, cck = c & 31, jk = cck ^ (rk & 7);                      \
      gload_lds16(kbase + (size_t)((t) * 64 + rk) * 256 + jk * 8,              \
                  (char*)&Kbuf[s][0] + (i2 * 512 + w * 64) * 16);              \
      int rd = c >> 3, ccv = c & 7, jv = ccv ^ (rd & 7);                       \
      gload_lds16(vbase + (size_t)rd * L_ + (t) * 64 + jv * 8,                 \
                  (char*)&Vbuf[s][0] + (i2 * 512 + w * 64) * 16);              \
    }                                                                          \
  }

  // issue tile-0 staging FIRST — DMA in flight during the rope chain below
  STAGE(0, 0);

  // Q fragments from qkvproj (un-roped); rope via table, scale folded.
  const int lpos = q0 + l15;
  const u16* qrow = qkv + ((size_t)(b * 2048 + lpos) * 2560 + h * 256);
  short8x qf[8];
#pragma unroll
  for (int kc = 0; kc < 8; ++kc)
    qf[kc] = *(const short8x*)(qrow + kc * 32 + l4 * 8);
#pragma unroll
  for (int kc = 0; kc < 4; ++kc) {
    short8x lo = qf[kc], hi = qf[kc + 4];
#pragma unroll
    for (int jj = 0; jj < 8; ++jj) {
      int d = kc * 32 + l4 * 8 + jj;
      float2 cs = tab[lpos * 128 + d];
      float x1 = bf2f((u16)lo[jj]), x2 = bf2f((u16)hi[jj]);
      lo[jj] = (short)f2bf((x1 * cs.x - x2 * cs.y) * 0.0625f);
      hi[jj] = (short)f2bf((x2 * cs.x + x1 * cs.y) * 0.0625f);
    }
    qf[kc] = lo;
    qf[kc + 4] = hi;
  }

  f32x4 o[16] = {};
  float mrow = -3e38f, srow = 0.f;    // per-lane: q-row = l15

  asm volatile("s_waitcnt vmcnt(0)" ::: "memory");
  __syncthreads();

  for (int t = 0; t < nt; ++t) {
    if (t + 1 < nt) STAGE(t + 1, (t + 1) & 1);  // prefetch lands under compute
    if (t <= j) {
      const char* Kb = (const char*)&Kbuf[t & 1][0];
      const char* Vb = (const char*)&Vbuf[t & 1][0];

      // S^T = K Q^T : C row = kv (n*16 + l4*4+r), col = q (l15)
      f32x4 sacc[4] = {};
      __builtin_amdgcn_s_setprio(1);
#pragma unroll
      for (int kc = 0; kc < 8; ++kc)
#pragma unroll
        for (int n = 0; n < 4; ++n) {
          int row = n * 16 + l15;
          short8x kf = *(const short8x*)(Kb +
              ((row * 512 + kc * 64 + l4 * 16) ^ ((row & 7) << 4)));
          sacc[n] = __builtin_amdgcn_mfma_f32_16x16x32_bf16(kf, qf[kc], sacc[n], 0, 0, 0);
        }
      __builtin_amdgcn_s_setprio(0);
      // mask + in-lane softmax for q-row l15 (lane holds 16 kv values)
      float pp[4][4];
      const bool dm = (t == j);
      const int qg = q0 + l15;
      float pm = -3e38f;
#pragma unroll
      for (int n = 0; n < 4; ++n)
#pragma unroll
        for (int r = 0; r < 4; ++r) {
          int kvg = t * 64 + n * 16 + l4 * 4 + r;
          float v = sacc[n][r];
          if (dm && (kvg > qg)) v = -1e30f;
          pp[n][r] = v;
          pm = fmaxf(pm, v);
        }
      pm = fmaxf(pm, __shfl_xor(pm, 16));
      pm = fmaxf(pm, __shfl_xor(pm, 32));
      // T13: skip rescale when max didn't grow past threshold (P <= e^8, safe)
      const bool defer = __all(pm <= mrow + 8.f);
      float mn, alpha;
      if (defer) {
        mn = mrow;
      } else {
        mn = fmaxf(mrow, pm);
        alpha = __expf(mrow - mn);
        mrow = mn;
      }
      float rs = 0.f;
#pragma unroll
      for (int n = 0; n < 4; ++n)
#pragma unroll
        for (int r = 0; r < 4; ++r) {
          pp[n][r] = __expf(pp[n][r] - mn);
          rs += pp[n][r];
        }
      rs += __shfl_xor(rs, 16);
      rs += __shfl_xor(rs, 32);
      if (defer) {
        srow += rs;
      } else {
        srow = srow * alpha + rs;
        float av[4];
#pragma unroll
        for (int r = 0; r < 4; ++r)
          av[r] = __shfl(alpha, l4 * 4 + r, 16);
#pragma unroll
        for (int ff = 0; ff < 16; ++ff) {
          o[ff][0] *= av[0]; o[ff][1] *= av[1];
          o[ff][2] *= av[2]; o[ff][3] *= av[3];
        }
      }
      // P -> Ps [q=l15][kv], XOR-swizzled, packed pairs via v_cvt_pk_bf16_f32
#pragma unroll
      for (int n = 0; n < 4; ++n)
#pragma unroll
        for (int r = 0; r < 4; r += 2) {
          unsigned pk;
          asm("v_cvt_pk_bf16_f32 %0, %1, %2" : "=v"(pk) : "v"(pp[n][r]), "v"(pp[n][r + 1]));
          *(unsigned*)((char*)Ps + w * 2048 +
                       ((l15 * 128 + (n * 16 + l4 * 4 + r) * 2) ^ ((l15 & 7) << 4))) = pk;
        }
      asm volatile("s_waitcnt lgkmcnt(0)" ::: "memory");
      short8x paf[2];
#pragma unroll
      for (int kc2 = 0; kc2 < 2; ++kc2)
        paf[kc2] = *(const short8x*)((const char*)Ps + w * 2048 +
            ((l15 * 128 + kc2 * 64 + l4 * 16) ^ ((l15 & 7) << 4)));
      // O += P V : contraction over kv=64
      __builtin_amdgcn_s_setprio(1);
#pragma unroll
      for (int kc2 = 0; kc2 < 2; ++kc2)
#pragma unroll
        for (int ff = 0; ff < 16; ++ff) {
          int rd = ff * 16 + l15;
          short8x vf = *(const short8x*)(Vb +
              ((rd * 128 + kc2 * 64 + l4 * 16) ^ ((rd & 7) << 4)));
          o[ff] = __builtin_amdgcn_mfma_f32_16x16x32_bf16(paf[kc2], vf, o[ff], 0, 0, 0);
        }
      __builtin_amdgcn_s_setprio(0);
    }
    // prefetch (issued at step start) complete + all waves done reading bufs
    asm volatile("s_waitcnt vmcnt(0)" ::: "memory");
    __syncthreads();
  }
  // epilogue: srow keyed by q=l15; o rows are q=l4*4+r
  float sv[4];
#pragma unroll
  for (int r = 0; r < 4; ++r)
    sv[r] = __shfl(srow, l4 * 4 + r, 16);
#pragma unroll
  for (int r = 0; r < 4; ++r) {
    float inv = 1.0f / sv[r];
    int grow = q0 + l4 * 4 + r;
    size_t base = ((size_t)b * L_ + grow) * (size_t)(H_ * HD_) + h * 256;
#pragma unroll
    for (int ff = 0; ff < 16; ++ff)
      attn_o[base + ff * 16 + l15] = f2bf(o[ff][r] * inv);
  }
#undef STAGE
}

extern "C" void kernel_launch(void* const* d_in, const int* in_sizes, int n_in,
                              void* d_out, int out_size, void* d_ws, size_t ws_size,
                              hipStream_t stream) {
  const float* x  = (const float*)d_in[0];
  const float* Wq = (const float*)d_in[1];
  const float* Wk = (const float*)d_in[2];
  const float* Wv = (const float*)d_in[3];
  const float* Wo = (const float*)d_in[4];
  // d_in[5] = additive causal mask: semantics reproduced analytically, not read.
  float* out = (float*)d_out;
  char* ws = (char*)d_ws;
  size_t off = 0;
  auto alloc = [&](size_t bytes) {
    void* p = ws + off;
    off = (off + bytes + 255) & ~(size_t)255;
    return p;
  };
  u16* wqkv_t  = (u16*)alloc(2560ull * 2048 * 2);  // rows: 0..2047 Wq^T | 2048..2303 Wk^T | 2304..2559 Wv^T
  u16* wo_t    = (u16*)alloc(2048ull * 2048 * 2);
  u16* xbf     = (u16*)alloc(4096ull * 2048 * 2);  // reused as attn_o after QKV proj
  u16* qkvproj = (u16*)alloc(4096ull * 2560 * 2);  // [B*L][2560]: Q|K|V (Q read in-place by flash)
  u16* kb      = (u16*)alloc(4096ull * 256 * 2);
  u16* vtb     = (u16*)alloc(4096ull * 256 * 2);
  float2* rtab = (float2*)alloc(2048ull * 128 * 8);
  u16* attn_o  = xbf;  // alias: xbf dead after QKV projection

  cvt_x_kernel<<<8192, 256, 0, stream>>>((const float4*)x, xbf);
  rope_tab_kernel<<<1024, 256, 0, stream>>>(rtab);
  cvt_wt_kernel<<<dim3(64, 64), dim3(32, 8), 0, stream>>>(Wq, wqkv_t, 2048, 2048);
  cvt_wt_kernel<<<dim3(8, 64),  dim3(32, 8), 0, stream>>>(Wk, wqkv_t + 2048ull * 2048, 2048, 256);
  cvt_wt_kernel<<<dim3(8, 64),  dim3(32, 8), 0, stream>>>(Wv, wqkv_t + 2304ull * 2048, 2048, 256);
  cvt_wt_kernel<<<dim3(64, 64), dim3(32, 8), 0, stream>>>(Wo, wo_t, 2048, 2048);

  // fused QKV projection: M=4096, N=2560, K=2048 (grid 20x16 = 320 blocks)
  gemmtb_kernel<0><<<dim3(20, 16), 512, 0, stream>>>(xbf, wqkv_t, qkvproj, 4096, 2560, 2048);

  // merged K-rope + V-transpose: z 0..1 = V-transpose batches, z 2..3 = K rope
  prep_kv_kernel<<<dim3(1024, 8, 4), 256, 0, stream>>>(qkvproj, kb, vtb, rtab);

  flash_kernel<<<256, 512, 0, stream>>>(qkvproj, kb, vtb, rtab, attn_o);

  // O projection: M=4096, N=2048, K=2048 (grid 16x16 = 256 blocks, 100% fill)
  gemmtb_kernel<1><<<dim3(16, 16), 512, 0, stream>>>(attn_o, wo_t, out, 4096, 2048, 2048);
}

// Round 19
// 219.085 us; speedup vs baseline: 1.0778x; 1.0778x over previous
//
#include <hip/hip_runtime.h>

typedef unsigned short u16;
typedef __attribute__((ext_vector_type(8))) short short8x;
typedef __attribute__((ext_vector_type(4))) float f32x4;

#define B_ 2
#define L_ 2048
#define HID_ 2048
#define H_ 8
#define HD_ 256

__device__ __forceinline__ u16 f2bf(float f) {
  union { float f; unsigned u; } v; v.f = f;
  unsigned r = v.u + 0x7FFFu + ((v.u >> 16) & 1u);
  return (u16)(r >> 16);
}
__device__ __forceinline__ float bf2f(u16 u) {
  union { unsigned u; float f; } v; v.u = ((unsigned)u) << 16;
  return v.f;
}

// async global->LDS, 16B per lane. lds ptr must be the wave-uniform base;
// HW adds lane*16.
__device__ __forceinline__ void gload_lds16(const void* g, void* l) {
  __builtin_amdgcn_global_load_lds((const __attribute__((address_space(1))) unsigned*)g,
                                   (__attribute__((address_space(3))) unsigned*)l, 16, 0, 0);
}

// x fp32 -> bf16, same layout. grid = nelem/4/256
__global__ __launch_bounds__(256) void cvt_x_kernel(const float4* __restrict__ in,
                                                    u16* __restrict__ out) {
  int idx = blockIdx.x * 256 + threadIdx.x;
  float4 v = in[idx];
  u16* o = out + (size_t)idx * 4;
  o[0] = f2bf(v.x); o[1] = f2bf(v.y); o[2] = f2bf(v.z); o[3] = f2bf(v.w);
}

// W fp32 [K][N] -> Wt bf16 [N][K] (row stride K). grid (N/32, K/32), block (32,8)
__global__ __launch_bounds__(256) void cvt_wt_kernel(const float* __restrict__ W,
                                                     u16* __restrict__ Wt, int K, int N) {
  __shared__ float tile[32][33];
  int n0 = blockIdx.x * 32, k0 = blockIdx.y * 32;
  int tx = threadIdx.x, ty = threadIdx.y;
#pragma unroll
  for (int i = 0; i < 32; i += 8)
    tile[ty + i][tx] = W[(size_t)(k0 + ty + i) * N + n0 + tx];
  __syncthreads();
#pragma unroll
  for (int i = 0; i < 32; i += 8)
    Wt[(size_t)(n0 + ty + i) * K + k0 + tx] = f2bf(tile[tx][ty + i]);
}

// RoPE + head-permute (K only now; Q rope is fused into flash).
__global__ __launch_bounds__(256) void rope_kernel(const u16* __restrict__ in,
                                                   u16* __restrict__ out, int nh_shift,
                                                   int in_stride, int in_off, float scale) {
  int idx = blockIdx.x * 256 + threadIdx.x;
  int nh = 1 << nh_shift;
  int d = idx & 127;
  int t = idx >> 7;
  int h = t & (nh - 1);
  int row = t >> nh_shift;  // b*L + l
  int l = row & (L_ - 1);
  int b = row >> 11;
  size_t ibase = (size_t)row * in_stride + in_off + h * 256 + d;
  float x1 = bf2f(in[ibase]);
  float x2 = bf2f(in[ibase + 128]);
  float f = exp2f(-(float)d * (13.287712379549449f / 128.0f));
  float ang = (float)l * f;
  float s, c;
  sincosf(ang, &s, &c);
  size_t obase = ((size_t)(b * nh + h) * L_ + l) * 256 + d;
  out[obase] = f2bf((x1 * c - x2 * s) * scale);
  out[obase + 128] = f2bf((x2 * c + x1 * s) * scale);
}

// qkvproj bf16 [B*L][2560] (V at col 2304) -> vt bf16 [(b*256+d)][L].
// 32x32 LDS tile transpose. grid (L/32, 256/32, B), block (32,8)
__global__ __launch_bounds__(256) void vt_kernel(const u16* __restrict__ qkvproj,
                                                 u16* __restrict__ vt) {
  __shared__ u16 tile[32][33];
  int l0 = blockIdx.x * 32, d0 = blockIdx.y * 32, b = blockIdx.z;
  int tx = threadIdx.x, ty = threadIdx.y;
#pragma unroll
  for (int i = 0; i < 32; i += 8)
    tile[ty + i][tx] = qkvproj[((size_t)b * 2048 + l0 + ty + i) * 2560 + 2304 + d0 + tx];
  __syncthreads();
#pragma unroll
  for (int i = 0; i < 32; i += 8)
    vt[((size_t)b * 256 + d0 + ty + i) * 2048 + l0 + tx] = tile[tx][ty + i];
}

// C[M][N] = A[M][K] @ Bt[N][K]^T — 256x128 tile, BK=64, 8 waves (4M x 2N,
// wave = 64x64, acc[4][4]), TRIPLE-buffered staging with counted vmcnt (T4).
// (R13 config — best measured on these shapes; 256² template lost to fill.)
template <int F32OUT>
__global__ __launch_bounds__(512) void gemmtb_kernel(const u16* __restrict__ A,
                                                     const u16* __restrict__ Bt,
                                                     void* __restrict__ Cv,
                                                     int M, int N, int K) {
  __shared__ __attribute__((aligned(16))) u16 As[3][256 * 64];
  __shared__ __attribute__((aligned(16))) u16 Bs[3][128 * 64];
  const int tid = threadIdx.x, lane = tid & 63, w = tid >> 6;
  const int wr = w >> 1, wc = w & 1;
  const int l15 = lane & 15, l4 = lane >> 4;
  // XCD-aware swizzle (bijective; nwg%8==0 in all our launches)
  const int nbx = gridDim.x;
  int flat = blockIdx.y * nbx + blockIdx.x;
  int nwg = nbx * gridDim.y;
  int q8 = nwg >> 3, r8 = nwg & 7;
  int xcd = flat & 7, idx8 = flat >> 3;
  int neu = (xcd < r8 ? xcd * (q8 + 1) : r8 * (q8 + 1) + (xcd - r8) * q8) + idx8;
  const int m0 = (neu / nbx) * 256, n0 = (neu % nbx) * 128;
  const int NT = K >> 6;

  f32x4 acc[4][4] = {};
  short8x a[4][2], b[4][2];

#define STAGE_A(t, s)                                                           \
  {                                                                             \
    _Pragma("unroll") for (int i = 0; i < 4; ++i) {                             \
      int c = i * 512 + tid;                                                    \
      int row = c >> 3, j = (c & 7) ^ (row & 7);                                \
      gload_lds16(A + (size_t)(m0 + row) * K + (t) * 64 + j * 8,                \
                  (char*)&As[s][0] + (i * 512 + w * 64) * 16);                  \
    }                                                                           \
  }
#define STAGE_B(t, s)                                                           \
  {                                                                             \
    _Pragma("unroll") for (int i = 0; i < 2; ++i) {                             \
      int c = i * 512 + tid;                                                    \
      int row = c >> 3, j = (c & 7) ^ (row & 7);                                \
      gload_lds16(Bt + (size_t)(n0 + row) * K + (t) * 64 + j * 8,               \
                  (char*)&Bs[s][0] + (i * 512 + w * 64) * 16);                  \
    }                                                                           \
  }
#define RD_A(s, mi, ks)                                                         \
  (*(const short8x*)((const char*)&As[s][0] +                                   \
      ((((wr * 64 + (mi) * 16 + l15) * 128 + ((ks) * 4 + l4) * 16)) ^           \
       ((l15 & 7) << 4))))
#define RD_B(s, ni, ks)                                                         \
  (*(const short8x*)((const char*)&Bs[s][0] +                                   \
      ((((wc * 64 + (ni) * 16 + l15) * 128 + ((ks) * 4 + l4) * 16)) ^           \
       ((l15 & 7) << 4))))

  // prologue: stage tiles 0 and 1; wait tile 0 (newest 6 = tile 1's loads)
  STAGE_A(0, 0);
  STAGE_B(0, 0);
  STAGE_A(1, 1);
  STAGE_B(1, 1);
  asm volatile("s_waitcnt vmcnt(6)" ::: "memory");
  __builtin_amdgcn_s_barrier();

  for (int t = 0; t < NT; ++t) {
    const int cur = t % 3, nxt = (t + 2) % 3;
    const bool ns = (t + 2 < NT);
    // ---- P1: read A-frags + B-lo; issue A-stage(t+2); MFMA n-lo
#pragma unroll
    for (int mi = 0; mi < 4; ++mi) { a[mi][0] = RD_A(cur, mi, 0); a[mi][1] = RD_A(cur, mi, 1); }
#pragma unroll
    for (int ni = 0; ni < 2; ++ni) { b[ni][0] = RD_B(cur, ni, 0); b[ni][1] = RD_B(cur, ni, 1); }
    if (ns) STAGE_A(t + 2, nxt);
    __builtin_amdgcn_s_barrier();
    __builtin_amdgcn_s_setprio(1);
#pragma unroll
    for (int mi = 0; mi < 4; ++mi)
#pragma unroll
      for (int ni = 0; ni < 2; ++ni) {
        acc[mi][ni] = __builtin_amdgcn_mfma_f32_16x16x32_bf16(a[mi][0], b[ni][0], acc[mi][ni], 0, 0, 0);
        acc[mi][ni] = __builtin_amdgcn_mfma_f32_16x16x32_bf16(a[mi][1], b[ni][1], acc[mi][ni], 0, 0, 0);
      }
    __builtin_amdgcn_s_setprio(0);
    __builtin_amdgcn_s_barrier();
    // ---- P2: read B-hi; issue B-stage(t+2); MFMA n-hi; counted vmcnt
#pragma unroll
    for (int ni = 2; ni < 4; ++ni) { b[ni][0] = RD_B(cur, ni, 0); b[ni][1] = RD_B(cur, ni, 1); }
    if (ns) STAGE_B(t + 2, nxt);
    __builtin_amdgcn_s_barrier();
    __builtin_amdgcn_s_setprio(1);
#pragma unroll
    for (int mi = 0; mi < 4; ++mi)
#pragma unroll
      for (int ni = 2; ni < 4; ++ni) {
        acc[mi][ni] = __builtin_amdgcn_mfma_f32_16x16x32_bf16(a[mi][0], b[ni][0], acc[mi][ni], 0, 0, 0);
        acc[mi][ni] = __builtin_amdgcn_mfma_f32_16x16x32_bf16(a[mi][1], b[ni][1], acc[mi][ni], 0, 0, 0);
      }
    __builtin_amdgcn_s_setprio(0);
    // ensure tile t+1 fully landed; keep tile t+2's 6 loads in flight
    if (ns) asm volatile("s_waitcnt vmcnt(6)" ::: "memory");
    else    asm volatile("s_waitcnt vmcnt(0)" ::: "memory");
    __builtin_amdgcn_s_barrier();
  }
  // epilogue: C row = (lane>>4)*4+r, col = lane&15 (m89-verified mapping)
#pragma unroll
  for (int mi = 0; mi < 4; ++mi) {
#pragma unroll
    for (int ni = 0; ni < 4; ++ni) {
      int gcol = n0 + wc * 64 + ni * 16 + l15;
#pragma unroll
      for (int r = 0; r < 4; ++r) {
        int grow = m0 + wr * 64 + mi * 16 + l4 * 4 + r;
        if (F32OUT)
          ((float*)Cv)[(size_t)grow * N + gcol] = acc[mi][ni][r];
        else
          ((u16*)Cv)[(size_t)grow * N + gcol] = f2bf(acc[mi][ni][r]);
      }
    }
  }
#undef STAGE_A
#undef STAGE_B
#undef RD_A
#undef RD_B
}

// Flash attention v13 — 8-wave blocks, heavy/light q-block pairing in-block,
// K+V dbuf with prefetch, fused in-register Q-RoPE. (Champion config, R15.)
// qkv: [B*L][2560] (Q at col h*256, un-roped), kb: [B][L][256] (roped),
// vt: [B][256][L], attn_o: [B*L][H*256].
__global__ __launch_bounds__(512) void flash_kernel(const u16* __restrict__ qkv,
                                                    const u16* __restrict__ kb,
                                                    const u16* __restrict__ vt,
                                                    u16* __restrict__ attn_o) {
  __shared__ __attribute__((aligned(16))) u16 Kbuf[2][64 * 256];  // [k][d], read ^(k&7)<<4
  __shared__ __attribute__((aligned(16))) u16 Vbuf[2][256 * 64];  // [d][k], read ^(d&7)<<4
  __shared__ __attribute__((aligned(16))) u16 Ps[8 * 16 * 64];    // per-wave [q16][kv64], ^(q&7)<<4
  const int x = blockIdx.x;
  const int p = x >> 4;               // pair index 0..15
  const int bh = x & 15;
  const int b = bh >> 3;
  const int h = bh & 7;
  const int tid = threadIdx.x, lane = tid & 63, w = tid >> 6;
  const int l15 = lane & 15, l4 = lane >> 4;
  const int j = (w < 4) ? (31 - p) : p;   // this wave's 64-row q-block
  const int q0 = j * 64 + (w & 3) * 16;
  const int nt = (31 - p) + 1;            // shared k-step count (heavy bound)

  // Q fragments straight from qkvproj (un-roped), then rope in-register
  const int lpos = q0 + l15;
  const u16* qrow = qkv + ((size_t)(b * 2048 + lpos) * 2560 + h * 256);
  short8x qf[8];
#pragma unroll
  for (int kc = 0; kc < 8; ++kc)
    qf[kc] = *(const short8x*)(qrow + kc * 32 + l4 * 8);
#pragma unroll
  for (int kc = 0; kc < 4; ++kc) {
    short8x lo = qf[kc], hi = qf[kc + 4];
#pragma unroll
    for (int jj = 0; jj < 8; ++jj) {
      int d = kc * 32 + l4 * 8 + jj;
      float f = exp2f(-(float)d * (13.287712379549449f / 128.0f));
      float ang = (float)lpos * f;
      float s, c;
      sincosf(ang, &s, &c);
      float x1 = bf2f((u16)lo[jj]), x2 = bf2f((u16)hi[jj]);
      lo[jj] = (short)f2bf((x1 * c - x2 * s) * 0.0625f);
      hi[jj] = (short)f2bf((x2 * c + x1 * s) * 0.0625f);
    }
    qf[kc] = lo;
    qf[kc + 4] = hi;
  }

  f32x4 o[16] = {};
  float mrow = -3e38f, srow = 0.f;    // per-lane: q-row = l15

  const u16* kbase = kb + (size_t)b * (L_ * 256);
  const u16* vbase = vt + (size_t)b * (256 * L_);

#define STAGE(t, s)                                                            \
  {                                                                            \
    _Pragma("unroll") for (int i2 = 0; i2 < 4; ++i2) {                         \
      int c = i2 * 512 + tid;                                                  \
      int rk = c >> 5, cck = c & 31, jk = cck ^ (rk & 7);                      \
      gload_lds16(kbase + (size_t)((t) * 64 + rk) * 256 + jk * 8,              \
                  (char*)&Kbuf[s][0] + (i2 * 512 + w * 64) * 16);              \
      int rd = c >> 3, ccv = c & 7, jv = ccv ^ (rd & 7);                       \
      gload_lds16(vbase + (size_t)rd * L_ + (t) * 64 + jv * 8,                 \
                  (char*)&Vbuf[s][0] + (i2 * 512 + w * 64) * 16);              \
    }                                                                          \
  }

  STAGE(0, 0);
  asm volatile("s_waitcnt vmcnt(0)" ::: "memory");
  __syncthreads();

  for (int t = 0; t < nt; ++t) {
    if (t + 1 < nt) STAGE(t + 1, (t + 1) & 1);  // prefetch lands under compute
    if (t <= j) {
      const char* Kb = (const char*)&Kbuf[t & 1][0];
      const char* Vb = (const char*)&Vbuf[t & 1][0];

      // S^T = K Q^T : C row = kv (n*16 + l4*4+r), col = q (l15)
      f32x4 sacc[4] = {};
      __builtin_amdgcn_s_setprio(1);
#pragma unroll
      for (int kc = 0; kc < 8; ++kc)
#pragma unroll
        for (int n = 0; n < 4; ++n) {
          int row = n * 16 + l15;
          short8x kf = *(const short8x*)(Kb +
              ((row * 512 + kc * 64 + l4 * 16) ^ ((row & 7) << 4)));
          sacc[n] = __builtin_amdgcn_mfma_f32_16x16x32_bf16(kf, qf[kc], sacc[n], 0, 0, 0);
        }
      __builtin_amdgcn_s_setprio(0);
      // mask + in-lane softmax for q-row l15 (lane holds 16 kv values)
      float pp[4][4];
      const bool dm = (t == j);
      const int qg = q0 + l15;
      float pm = -3e38f;
#pragma unroll
      for (int n = 0; n < 4; ++n)
#pragma unroll
        for (int r = 0; r < 4; ++r) {
          int kvg = t * 64 + n * 16 + l4 * 4 + r;
          float v = sacc[n][r];
          if (dm && (kvg > qg)) v = -1e30f;
          pp[n][r] = v;
          pm = fmaxf(pm, v);
        }
      pm = fmaxf(pm, __shfl_xor(pm, 16));
      pm = fmaxf(pm, __shfl_xor(pm, 32));
      // T13: skip rescale when max didn't grow past threshold (P <= e^8, safe)
      const bool defer = __all(pm <= mrow + 8.f);
      float mn, alpha;
      if (defer) {
        mn = mrow;
      } else {
        mn = fmaxf(mrow, pm);
        alpha = __expf(mrow - mn);
        mrow = mn;
      }
      float rs = 0.f;
#pragma unroll
      for (int n = 0; n < 4; ++n)
#pragma unroll
        for (int r = 0; r < 4; ++r) {
          pp[n][r] = __expf(pp[n][r] - mn);
          rs += pp[n][r];
        }
      rs += __shfl_xor(rs, 16);
      rs += __shfl_xor(rs, 32);
      if (defer) {
        srow += rs;
      } else {
        srow = srow * alpha + rs;
        float av[4];
#pragma unroll
        for (int r = 0; r < 4; ++r)
          av[r] = __shfl(alpha, l4 * 4 + r, 16);
#pragma unroll
        for (int ff = 0; ff < 16; ++ff) {
          o[ff][0] *= av[0]; o[ff][1] *= av[1];
          o[ff][2] *= av[2]; o[ff][3] *= av[3];
        }
      }
      // P -> Ps [q=l15][kv], XOR-swizzled, packed pairs via v_cvt_pk_bf16_f32
#pragma unroll
      for (int n = 0; n < 4; ++n)
#pragma unroll
        for (int r = 0; r < 4; r += 2) {
          unsigned pk;
          asm("v_cvt_pk_bf16_f32 %0, %1, %2" : "=v"(pk) : "v"(pp[n][r]), "v"(pp[n][r + 1]));
          *(unsigned*)((char*)Ps + w * 2048 +
                       ((l15 * 128 + (n * 16 + l4 * 4 + r) * 2) ^ ((l15 & 7) << 4))) = pk;
        }
      asm volatile("s_waitcnt lgkmcnt(0)" ::: "memory");
      short8x paf[2];
#pragma unroll
      for (int kc2 = 0; kc2 < 2; ++kc2)
        paf[kc2] = *(const short8x*)((const char*)Ps + w * 2048 +
            ((l15 * 128 + kc2 * 64 + l4 * 16) ^ ((l15 & 7) << 4)));
      // O += P V : contraction over kv=64
      __builtin_amdgcn_s_setprio(1);
#pragma unroll
      for (int kc2 = 0; kc2 < 2; ++kc2)
#pragma unroll
        for (int ff = 0; ff < 16; ++ff) {
          int rd = ff * 16 + l15;
          short8x vf = *(const short8x*)(Vb +
              ((rd * 128 + kc2 * 64 + l4 * 16) ^ ((rd & 7) << 4)));
          o[ff] = __builtin_amdgcn_mfma_f32_16x16x32_bf16(paf[kc2], vf, o[ff], 0, 0, 0);
        }
      __builtin_amdgcn_s_setprio(0);
    }
    // prefetch (issued at step start) complete + all waves done reading bufs
    asm volatile("s_waitcnt vmcnt(0)" ::: "memory");
    __syncthreads();
  }
  // epilogue: srow keyed by q=l15; o rows are q=l4*4+r
  float sv[4];
#pragma unroll
  for (int r = 0; r < 4; ++r)
    sv[r] = __shfl(srow, l4 * 4 + r, 16);
#pragma unroll
  for (int r = 0; r < 4; ++r) {
    float inv = 1.0f / sv[r];
    int grow = q0 + l4 * 4 + r;
    size_t base = ((size_t)b * L_ + grow) * (size_t)(H_ * HD_) + h * 256;
#pragma unroll
    for (int ff = 0; ff < 16; ++ff)
      attn_o[base + ff * 16 + l15] = f2bf(o[ff][r] * inv);
  }
#undef STAGE
}

extern "C" void kernel_launch(void* const* d_in, const int* in_sizes, int n_in,
                              void* d_out, int out_size, void* d_ws, size_t ws_size,
                              hipStream_t stream) {
  const float* x  = (const float*)d_in[0];
  const float* Wq = (const float*)d_in[1];
  const float* Wk = (const float*)d_in[2];
  const float* Wv = (const float*)d_in[3];
  const float* Wo = (const float*)d_in[4];
  // d_in[5] = additive causal mask: semantics reproduced analytically, not read.
  float* out = (float*)d_out;
  char* ws = (char*)d_ws;
  size_t off = 0;
  auto alloc = [&](size_t bytes) {
    void* p = ws + off;
    off = (off + bytes + 255) & ~(size_t)255;
    return p;
  };
  u16* wqkv_t  = (u16*)alloc(2560ull * 2048 * 2);  // rows: 0..2047 Wq^T | 2048..2303 Wk^T | 2304..2559 Wv^T
  u16* wo_t    = (u16*)alloc(2048ull * 2048 * 2);
  u16* xbf     = (u16*)alloc(4096ull * 2048 * 2);  // reused as attn_o after QKV proj
  u16* qkvproj = (u16*)alloc(4096ull * 2560 * 2);  // [B*L][2560]: Q|K|V (Q read in-place by flash)
  u16* kb      = (u16*)alloc(4096ull * 256 * 2);
  u16* vtb     = (u16*)alloc(4096ull * 256 * 2);
  u16* attn_o  = xbf;  // alias: xbf dead after QKV projection

  cvt_x_kernel<<<8192, 256, 0, stream>>>((const float4*)x, xbf);
  cvt_wt_kernel<<<dim3(64, 64), dim3(32, 8), 0, stream>>>(Wq, wqkv_t, 2048, 2048);
  cvt_wt_kernel<<<dim3(8, 64),  dim3(32, 8), 0, stream>>>(Wk, wqkv_t + 2048ull * 2048, 2048, 256);
  cvt_wt_kernel<<<dim3(8, 64),  dim3(32, 8), 0, stream>>>(Wv, wqkv_t + 2304ull * 2048, 2048, 256);
  cvt_wt_kernel<<<dim3(64, 64), dim3(32, 8), 0, stream>>>(Wo, wo_t, 2048, 2048);

  // fused QKV projection: M=4096, N=2560, K=2048 (grid 20x16 = 320 blocks)
  gemmtb_kernel<0><<<dim3(20, 16), 512, 0, stream>>>(xbf, wqkv_t, qkvproj, 4096, 2560, 2048);

  rope_kernel<<<2048, 256, 0, stream>>>(qkvproj, kb, 0, 2560, 2048, 1.0f);  // K only
  vt_kernel<<<dim3(64, 8, 2), dim3(32, 8), 0, stream>>>(qkvproj, vtb);

  flash_kernel<<<256, 512, 0, stream>>>(qkvproj, kb, vtb, attn_o);

  // O projection: M=4096, N=2048, K=2048 (grid 16x16 = 256 blocks, 100% fill)
  gemmtb_kernel<1><<<dim3(16, 16), 512, 0, stream>>>(attn_o, wo_t, out, 4096, 2048, 2048);
}